// Round 7
// baseline (699.613 us; speedup 1.0000x reference)
//
#include <hip/hip_runtime.h>
#include <hip/hip_bf16.h>

#define NN 100000     // nodes
#define NE 400000     // edges
#define DD 128        // feature dim
#define NG 4096       // graphs
#define NL 5          // layers
#define NF 11         // in features
#define GROWS 100096  // g rows rounded up to 128 (782 blocks * 128)

typedef __attribute__((ext_vector_type(8))) __bf16 bf16x8;
typedef __attribute__((ext_vector_type(4))) float f32x4;

// ---------------- preprocessing ----------------

__global__ void deg_kernel(const int* __restrict__ ei, int* __restrict__ deg) {
    int e = blockIdx.x * 256 + threadIdx.x;
    if (e < NE) atomicAdd(&deg[ei[NE + e]], 1);
}

// block scans 1024 elements (4 per thread), writes per-block total
__global__ void scan1_kernel(const int* __restrict__ deg, int* __restrict__ off,
                             int* __restrict__ bsums) {
    __shared__ int lds[256];
    int tid = threadIdx.x, b = blockIdx.x;
    int base = b * 1024 + tid * 4;
    int v[4];
#pragma unroll
    for (int q = 0; q < 4; ++q) {
        int i = base + q;
        v[q] = (i < NN) ? deg[i] : 0;
    }
    int s = v[0] + v[1] + v[2] + v[3];
    lds[tid] = s;
    __syncthreads();
    for (int o = 1; o < 256; o <<= 1) {
        int t2 = (tid >= o) ? lds[tid - o] : 0;
        __syncthreads();
        lds[tid] += t2;
        __syncthreads();
    }
    int p = lds[tid] - s;  // exclusive prefix for this thread
#pragma unroll
    for (int q = 0; q < 4; ++q) {
        int i = base + q;
        if (i < NN) off[i] = p;
        p += v[q];
    }
    if (tid == 255) bsums[b] = lds[255];
}

__global__ void scan2_kernel(int* __restrict__ bsums, int nb) {
    __shared__ int lds[128];
    int tid = threadIdx.x;
    int v = (tid < nb) ? bsums[tid] : 0;
    lds[tid] = v;
    __syncthreads();
    for (int o = 1; o < 128; o <<= 1) {
        int t2 = (tid >= o) ? lds[tid - o] : 0;
        __syncthreads();
        lds[tid] += t2;
        __syncthreads();
    }
    if (tid < nb) bsums[tid] = lds[tid] - v;  // exclusive
}

__global__ void finish_kernel(int* __restrict__ off, const int* __restrict__ bsums,
                              const int* __restrict__ deg, float* __restrict__ dinv) {
    int i = blockIdx.x * 256 + threadIdx.x;
    if (i == 0) off[NN] = NE;
    if (i < NN) {
        off[i] += bsums[i >> 10];
        dinv[i] = rsqrtf((float)deg[i] + 2.0f);
    }
}

// packed CSR record: .x = src index, .y = bitcast(norm)
__global__ void fill_kernel(const int* __restrict__ ei, const int* __restrict__ off,
                            int* __restrict__ cursor, int2* __restrict__ csr,
                            const float* __restrict__ dinv) {
    int e = blockIdx.x * 256 + threadIdx.x;
    if (e >= NE) return;
    int s = ei[e];
    int d = ei[NE + e];
    int pos = off[d] + atomicAdd(&cursor[d], 1);
    csr[pos] = make_int2(s, __float_as_int(dinv[s] * dinv[d]));
}

// ---------------- W pre-pack: fragment-order bf16 hi/lo, once per launch ----------------
// Layout per layer: [ct(8)][kc(4)][lane(64)][i(8)]; B slot (lane,i) holds
// W[kc*32 + 8*(lane>>4) + i][ct*16 + (lane&15)]  (same k-map as the A-frag pack).

__global__ void wpack_kernel(const float* __restrict__ Wg, unsigned short* __restrict__ whi,
                             unsigned short* __restrict__ wlo) {
    int t = blockIdx.x * 256 + threadIdx.x;  // < NL*16384
    int l = t >> 14, r = t & 16383;
    int k = r >> 7, n = r & 127;
    float w = Wg[(size_t)l * 16384 + k * 128 + n];
    __bf16 hb = (__bf16)w;
    float lo = w - (float)hb;
    __bf16 lb = (__bf16)lo;
    int ct = n >> 4, kc = k >> 5, lane = (((k >> 3) & 3) << 4) | (n & 15), i = k & 7;
    size_t idx = (size_t)l * 16384 + (((ct * 4 + kc) * 64 + lane) * 8 + i);
    whi[idx] = __builtin_bit_cast(unsigned short, hb);
    wlo[idx] = __builtin_bit_cast(unsigned short, lb);
}

// ---------------- expansion: h = log(x+1) @ We + be ----------------

__global__ void expand_kernel(const float* __restrict__ x, const float* __restrict__ We,
                              const float* __restrict__ be, float* __restrict__ h) {
    int t = blockIdx.x * 256 + threadIdx.x;  // t < NN*128
    int i = t >> 7, j = t & 127;
    float acc = be[j];
#pragma unroll
    for (int f = 0; f < NF; ++f) {
        acc += __logf(x[i * NF + f] + 1.0f) * We[f * DD + j];
    }
    h[t] = acc;
}

// ---------------- aggregation: g = self_norm*h + sum_e enorm*h[src] ----------------
// 32 lanes per node (float4 per lane), 8 nodes per 256-block (round-2 proven version).

__global__ __launch_bounds__(256) void agg_kernel(const float* __restrict__ h,
                                                  float* __restrict__ g,
                                                  const int* __restrict__ off,
                                                  const int2* __restrict__ csr,
                                                  const float* __restrict__ dinv) {
    const int tid = threadIdx.x;
    const int node = blockIdx.x * 8 + (tid >> 5);
    const int jj = tid & 31;
    const float4* __restrict__ h4 = (const float4*)h;

    float di = dinv[node];
    float sn = 2.0f * di * di;
    float4 hv = h4[(size_t)node * 32 + jj];
    float4 acc = make_float4(sn * hv.x, sn * hv.y, sn * hv.z, sn * hv.w);

    int e = off[node];
    const int e1 = off[node + 1];
    for (; e + 4 <= e1; e += 4) {
        int2 p0 = csr[e], p1 = csr[e + 1], p2 = csr[e + 2], p3 = csr[e + 3];
        float4 v0 = h4[(size_t)p0.x * 32 + jj];
        float4 v1 = h4[(size_t)p1.x * 32 + jj];
        float4 v2 = h4[(size_t)p2.x * 32 + jj];
        float4 v3 = h4[(size_t)p3.x * 32 + jj];
        float w0 = __int_as_float(p0.y), w1 = __int_as_float(p1.y);
        float w2 = __int_as_float(p2.y), w3 = __int_as_float(p3.y);
        acc.x = fmaf(w0, v0.x, acc.x); acc.y = fmaf(w0, v0.y, acc.y);
        acc.z = fmaf(w0, v0.z, acc.z); acc.w = fmaf(w0, v0.w, acc.w);
        acc.x = fmaf(w1, v1.x, acc.x); acc.y = fmaf(w1, v1.y, acc.y);
        acc.z = fmaf(w1, v1.z, acc.z); acc.w = fmaf(w1, v1.w, acc.w);
        acc.x = fmaf(w2, v2.x, acc.x); acc.y = fmaf(w2, v2.y, acc.y);
        acc.z = fmaf(w2, v2.z, acc.z); acc.w = fmaf(w2, v2.w, acc.w);
        acc.x = fmaf(w3, v3.x, acc.x); acc.y = fmaf(w3, v3.y, acc.y);
        acc.z = fmaf(w3, v3.z, acc.z); acc.w = fmaf(w3, v3.w, acc.w);
    }
    for (; e < e1; ++e) {
        int2 p = csr[e];
        float4 v = h4[(size_t)p.x * 32 + jj];
        float w = __int_as_float(p.y);
        acc.x = fmaf(w, v.x, acc.x); acc.y = fmaf(w, v.y, acc.y);
        acc.z = fmaf(w, v.z, acc.z); acc.w = fmaf(w, v.w, acc.w);
    }
    ((float4*)g)[(size_t)node * 32 + jj] = acc;
}

// ---------------- MFMA GEMM (split-bf16, 3 terms), in-place epilogue ----------------
// h[r][:] += relu(g[r][:] @ W + b)  for this block's 128 rows.
// 4 waves/block, wave = 32 rows x 128 cols, no LDS, no barriers.
// A-frag: lane holds g[row0+rt*16+(lane&15)][kc*32 + 8*(lane>>4) + i] (i=0..7),
// split into hi/lo bf16. B-frags from wpack'd layout (same k-map -> permutation-safe).
// C/D layout (HW-verified): col=lane&15, row=(lane>>4)*4+reg.

__global__ __launch_bounds__(256) void mfma_gemm(const float* __restrict__ g,
                                                 float* __restrict__ h,
                                                 const unsigned short* __restrict__ whi,
                                                 const unsigned short* __restrict__ wlo,
                                                 const float* __restrict__ b) {
    const int lane = threadIdx.x & 63;
    const int wv = threadIdx.x >> 6;
    const int row0 = blockIdx.x * 128 + wv * 32;
    const int ar = lane & 15;
    const int ak = (lane >> 4) * 8;

    f32x4 c[2][8];
#pragma unroll
    for (int rt = 0; rt < 2; ++rt)
#pragma unroll
        for (int ct = 0; ct < 8; ++ct) c[rt][ct] = (f32x4){0.f, 0.f, 0.f, 0.f};

#pragma unroll
    for (int kc = 0; kc < 4; ++kc) {
        bf16x8 ah[2], al[2];
#pragma unroll
        for (int rt = 0; rt < 2; ++rt) {
            const float* src = g + (size_t)(row0 + rt * 16 + ar) * DD + kc * 32 + ak;
            float4 f0 = *(const float4*)src;
            float4 f1 = *(const float4*)(src + 4);
            float fv[8] = {f0.x, f0.y, f0.z, f0.w, f1.x, f1.y, f1.z, f1.w};
#pragma unroll
            for (int i = 0; i < 8; ++i) {
                __bf16 hi = (__bf16)fv[i];
                float lo = fv[i] - (float)hi;
                ah[rt][i] = hi;
                al[rt][i] = (__bf16)lo;
            }
        }
#pragma unroll
        for (int ct = 0; ct < 8; ++ct) {
            size_t boff = (size_t)(((ct * 4 + kc) * 64 + lane) * 8);
            bf16x8 bh = *(const bf16x8*)(whi + boff);
            bf16x8 bl = *(const bf16x8*)(wlo + boff);
#pragma unroll
            for (int rt = 0; rt < 2; ++rt) {
                c[rt][ct] = __builtin_amdgcn_mfma_f32_16x16x32_bf16(ah[rt], bh, c[rt][ct], 0, 0, 0);
                c[rt][ct] = __builtin_amdgcn_mfma_f32_16x16x32_bf16(al[rt], bh, c[rt][ct], 0, 0, 0);
                c[rt][ct] = __builtin_amdgcn_mfma_f32_16x16x32_bf16(ah[rt], bl, c[rt][ct], 0, 0, 0);
            }
        }
    }

    const int crow = (lane >> 4) * 4;
    const int ccol = lane & 15;
#pragma unroll
    for (int rt = 0; rt < 2; ++rt) {
#pragma unroll
        for (int ct = 0; ct < 8; ++ct) {
            float bb = b[ct * 16 + ccol];
#pragma unroll
            for (int j = 0; j < 4; ++j) {
                int row = row0 + rt * 16 + crow + j;
                if (row < NN) {
                    size_t o = (size_t)row * DD + ct * 16 + ccol;
                    h[o] = h[o] + fmaxf(c[rt][ct][j] + bb, 0.f);
                }
            }
        }
    }
}

// ---------------- pool: out[batch[i]] += h[i]  (batch sorted) ----------------

__global__ void pool_kernel(const float* __restrict__ h, const int* __restrict__ batch,
                            float* __restrict__ out) {
    int j = threadIdx.x;  // 128
    int n0 = blockIdx.x * 64;
    float acc = 0.f;
    int prev = -1;
    for (int n = 0; n < 64; ++n) {
        int i = n0 + n;
        if (i >= NN) break;
        int bi = batch[i];
        if (bi != prev) {
            if (prev >= 0) atomicAdd(&out[(size_t)prev * DD + j], acc);
            acc = 0.f;
            prev = bi;
        }
        acc += h[(size_t)i * DD + j];
    }
    if (prev >= 0) atomicAdd(&out[(size_t)prev * DD + j], acc);
}

// ---------------- launch ----------------

static inline size_t align_up(size_t x, size_t a) { return (x + a - 1) & ~(a - 1); }

extern "C" void kernel_launch(void* const* d_in, const int* in_sizes, int n_in,
                              void* d_out, int out_size, void* d_ws, size_t ws_size,
                              hipStream_t stream) {
    const float* x   = (const float*)d_in[0];
    const int*   ei  = (const int*)d_in[1];
    const int*   bat = (const int*)d_in[2];
    const float* We  = (const float*)d_in[4];
    const float* be  = (const float*)d_in[5];
    const float* Wg  = (const float*)d_in[6];
    const float* bg  = (const float*)d_in[7];
    float* out = (float*)d_out;

    // workspace carve-up
    char* p = (char*)d_ws;
    size_t o = 0;
    float* h = (float*)(p + o);       o = align_up(o + (size_t)NN * DD * 4, 512);
    float* g = (float*)(p + o);       o = align_up(o + (size_t)GROWS * DD * 4, 512);
    float* dinv = (float*)(p + o);    o = align_up(o + (size_t)NN * 4, 512);
    int* deg = (int*)(p + o);         o = align_up(o + (size_t)NN * 4, 512);
    int* cursor = (int*)(p + o);      o = align_up(o + (size_t)NN * 4, 512);
    int* off = (int*)(p + o);         o = align_up(o + (size_t)(NN + 1) * 4, 512);
    int* bsums = (int*)(p + o);       o = align_up(o + 512, 512);
    int2* csr = (int2*)(p + o);       o = align_up(o + (size_t)NE * 8, 512);
    unsigned short* whi = (unsigned short*)(p + o); o = align_up(o + (size_t)NL * 16384 * 2, 512);
    unsigned short* wlo = (unsigned short*)(p + o); o = align_up(o + (size_t)NL * 16384 * 2, 512);
    (void)ws_size; (void)in_sizes; (void)n_in; (void)out_size;

    const int GRID_E = (NE + 255) / 256;          // 1563
    const int GRID_SCAN1 = (NN + 1023) / 1024;    // 98
    const int GRID_N256 = (NN + 255) / 256;       // 391
    const int GRID_ND = (size_t)NN * DD / 256;    // 50000
    const int GRID_AGG = NN / 8;                  // 12500
    const int GRID_GEMM = GROWS / 128;            // 782
    const int GRID_POOL = (NN + 63) / 64;         // 1563
    const int GRID_WPACK = NL * 16384 / 256;      // 320

    // zero deg + cursor (ws is poisoned 0xAA each call)
    hipMemsetAsync(deg, 0, (size_t)NN * 4, stream);
    hipMemsetAsync(cursor, 0, (size_t)NN * 4, stream);
    hipMemsetAsync(out, 0, (size_t)NG * DD * 4, stream);

    deg_kernel<<<GRID_E, 256, 0, stream>>>(ei, deg);
    scan1_kernel<<<GRID_SCAN1, 256, 0, stream>>>(deg, off, bsums);
    scan2_kernel<<<1, 128, 0, stream>>>(bsums, GRID_SCAN1);
    finish_kernel<<<GRID_N256, 256, 0, stream>>>(off, bsums, deg, dinv);
    fill_kernel<<<GRID_E, 256, 0, stream>>>(ei, off, cursor, csr, dinv);
    wpack_kernel<<<GRID_WPACK, 256, 0, stream>>>(Wg, whi, wlo);

    expand_kernel<<<GRID_ND, 256, 0, stream>>>(x, We, be, h);

    for (int l = 0; l < NL; ++l) {
        agg_kernel<<<GRID_AGG, 256, 0, stream>>>(h, g, off, csr, dinv);
        mfma_gemm<<<GRID_GEMM, 256, 0, stream>>>(g, h,
                                                 whi + (size_t)l * 16384,
                                                 wlo + (size_t)l * 16384,
                                                 bg + (size_t)l * DD);
    }

    pool_kernel<<<GRID_POOL, 128, 0, stream>>>(h, bat, out);
}

// Round 8
// 598.148 us; speedup vs baseline: 1.1696x; 1.1696x over previous
//
#include <hip/hip_runtime.h>
#include <hip/hip_bf16.h>

#define NN 100000     // nodes
#define NE 400000     // edges
#define DD 128        // feature dim
#define NG 4096       // graphs
#define NL 5          // layers
#define NF 11         // in features
#define GROWS 100096  // g rows rounded up to 64 (1564 blocks * 64)

typedef __attribute__((ext_vector_type(8))) __bf16 bf16x8;
typedef __attribute__((ext_vector_type(4))) float f32x4;

// ---------------- preprocessing ----------------

__global__ void deg_kernel(const int* __restrict__ ei, int* __restrict__ deg) {
    int e = blockIdx.x * 256 + threadIdx.x;
    if (e < NE) atomicAdd(&deg[ei[NE + e]], 1);
}

// block scans 1024 elements (4 per thread), writes per-block total
__global__ void scan1_kernel(const int* __restrict__ deg, int* __restrict__ off,
                             int* __restrict__ bsums) {
    __shared__ int lds[256];
    int tid = threadIdx.x, b = blockIdx.x;
    int base = b * 1024 + tid * 4;
    int v[4];
#pragma unroll
    for (int q = 0; q < 4; ++q) {
        int i = base + q;
        v[q] = (i < NN) ? deg[i] : 0;
    }
    int s = v[0] + v[1] + v[2] + v[3];
    lds[tid] = s;
    __syncthreads();
    for (int o = 1; o < 256; o <<= 1) {
        int t2 = (tid >= o) ? lds[tid - o] : 0;
        __syncthreads();
        lds[tid] += t2;
        __syncthreads();
    }
    int p = lds[tid] - s;  // exclusive prefix for this thread
#pragma unroll
    for (int q = 0; q < 4; ++q) {
        int i = base + q;
        if (i < NN) off[i] = p;
        p += v[q];
    }
    if (tid == 255) bsums[b] = lds[255];
}

__global__ void scan2_kernel(int* __restrict__ bsums, int nb) {
    __shared__ int lds[128];
    int tid = threadIdx.x;
    int v = (tid < nb) ? bsums[tid] : 0;
    lds[tid] = v;
    __syncthreads();
    for (int o = 1; o < 128; o <<= 1) {
        int t2 = (tid >= o) ? lds[tid - o] : 0;
        __syncthreads();
        lds[tid] += t2;
        __syncthreads();
    }
    if (tid < nb) bsums[tid] = lds[tid] - v;  // exclusive
}

__global__ void finish_kernel(int* __restrict__ off, const int* __restrict__ bsums,
                              const int* __restrict__ deg, float* __restrict__ dinv) {
    int i = blockIdx.x * 256 + threadIdx.x;
    if (i == 0) off[NN] = NE;
    if (i < NN) {
        off[i] += bsums[i >> 10];
        dinv[i] = rsqrtf((float)deg[i] + 2.0f);
    }
}

// packed CSR record: .x = src index, .y = bitcast(norm)
__global__ void fill_kernel(const int* __restrict__ ei, const int* __restrict__ off,
                            int* __restrict__ cursor, int2* __restrict__ csr,
                            const float* __restrict__ dinv) {
    int e = blockIdx.x * 256 + threadIdx.x;
    if (e >= NE) return;
    int s = ei[e];
    int d = ei[NE + e];
    int pos = off[d] + atomicAdd(&cursor[d], 1);
    csr[pos] = make_int2(s, __float_as_int(dinv[s] * dinv[d]));
}

// ---------------- W pre-pack: A-fragment-order bf16 hi/lo (W^T as MFMA A operand) ------
// Layout per layer: [ft(8)][kc(4)][lane(64)][i(8)]; slot (lane,i) holds
// A[row = ft*16 + (lane&15)][k = kc*32 + (lane>>4)*8 + i] = W[k][f].
// (Identical index formula to the previous B-pack; only the interpretation changed.)

__global__ void wpack_kernel(const float* __restrict__ Wg, unsigned short* __restrict__ whi,
                             unsigned short* __restrict__ wlo) {
    int t = blockIdx.x * 256 + threadIdx.x;  // < NL*16384
    int l = t >> 14, r = t & 16383;
    int k = r >> 7, n = r & 127;
    float w = Wg[(size_t)l * 16384 + k * 128 + n];
    __bf16 hb = (__bf16)w;
    float lo = w - (float)hb;
    __bf16 lb = (__bf16)lo;
    int ft = n >> 4, kc = k >> 5, lane = (((k >> 3) & 3) << 4) | (n & 15), i = k & 7;
    size_t idx = (size_t)l * 16384 + (((ft * 4 + kc) * 64 + lane) * 8 + i);
    whi[idx] = __builtin_bit_cast(unsigned short, hb);
    wlo[idx] = __builtin_bit_cast(unsigned short, lb);
}

// ---------------- expansion: h = log(x+1) @ We + be ----------------

__global__ void expand_kernel(const float* __restrict__ x, const float* __restrict__ We,
                              const float* __restrict__ be, float* __restrict__ h) {
    int t = blockIdx.x * 256 + threadIdx.x;  // t < NN*128
    int i = t >> 7, j = t & 127;
    float acc = be[j];
#pragma unroll
    for (int f = 0; f < NF; ++f) {
        acc += __logf(x[i * NF + f] + 1.0f) * We[f * DD + j];
    }
    h[t] = acc;
}

// ---------------- aggregation: g = self_norm*h + sum_e enorm*h[src] ----------------
// 32 lanes per node (float4 per lane), 8 nodes per 256-block (proven version).

__global__ __launch_bounds__(256) void agg_kernel(const float* __restrict__ h,
                                                  float* __restrict__ g,
                                                  const int* __restrict__ off,
                                                  const int2* __restrict__ csr,
                                                  const float* __restrict__ dinv) {
    const int tid = threadIdx.x;
    const int node = blockIdx.x * 8 + (tid >> 5);
    const int jj = tid & 31;
    const float4* __restrict__ h4 = (const float4*)h;

    float di = dinv[node];
    float sn = 2.0f * di * di;
    float4 hv = h4[(size_t)node * 32 + jj];
    float4 acc = make_float4(sn * hv.x, sn * hv.y, sn * hv.z, sn * hv.w);

    int e = off[node];
    const int e1 = off[node + 1];
    for (; e + 4 <= e1; e += 4) {
        int2 p0 = csr[e], p1 = csr[e + 1], p2 = csr[e + 2], p3 = csr[e + 3];
        float4 v0 = h4[(size_t)p0.x * 32 + jj];
        float4 v1 = h4[(size_t)p1.x * 32 + jj];
        float4 v2 = h4[(size_t)p2.x * 32 + jj];
        float4 v3 = h4[(size_t)p3.x * 32 + jj];
        float w0 = __int_as_float(p0.y), w1 = __int_as_float(p1.y);
        float w2 = __int_as_float(p2.y), w3 = __int_as_float(p3.y);
        acc.x = fmaf(w0, v0.x, acc.x); acc.y = fmaf(w0, v0.y, acc.y);
        acc.z = fmaf(w0, v0.z, acc.z); acc.w = fmaf(w0, v0.w, acc.w);
        acc.x = fmaf(w1, v1.x, acc.x); acc.y = fmaf(w1, v1.y, acc.y);
        acc.z = fmaf(w1, v1.z, acc.z); acc.w = fmaf(w1, v1.w, acc.w);
        acc.x = fmaf(w2, v2.x, acc.x); acc.y = fmaf(w2, v2.y, acc.y);
        acc.z = fmaf(w2, v2.z, acc.z); acc.w = fmaf(w2, v2.w, acc.w);
        acc.x = fmaf(w3, v3.x, acc.x); acc.y = fmaf(w3, v3.y, acc.y);
        acc.z = fmaf(w3, v3.z, acc.z); acc.w = fmaf(w3, v3.w, acc.w);
    }
    for (; e < e1; ++e) {
        int2 p = csr[e];
        float4 v = h4[(size_t)p.x * 32 + jj];
        float w = __int_as_float(p.y);
        acc.x = fmaf(w, v.x, acc.x); acc.y = fmaf(w, v.y, acc.y);
        acc.z = fmaf(w, v.z, acc.z); acc.w = fmaf(w, v.w, acc.w);
    }
    ((float4*)g)[(size_t)node * 32 + jj] = acc;
}

// ---------------- MFMA GEMM v2 (operand-swapped): D = W^T · g^T ----------------
// h[n][:] += relu((g@W)[n][:] + b)  -- computed as D[f][n] so the C/D fragment
// (col=lane&15 -> node, row=(lane>>4)*4+j -> 4 CONSECUTIVE features) lets the
// epilogue be pure float4. Wave = 16 nodes x 128 features, no LDS, no barriers.
// 3-term split: Whi*ghi + Wlo*ghi + Whi*glo (fp32 accum).

__global__ __launch_bounds__(256) void mfma_gemm(const float* __restrict__ g,
                                                 float* __restrict__ h,
                                                 const unsigned short* __restrict__ whi,
                                                 const unsigned short* __restrict__ wlo,
                                                 const float* __restrict__ b) {
    const int lane = threadIdx.x & 63;
    const int wv = threadIdx.x >> 6;
    const int node = blockIdx.x * 64 + wv * 16 + (lane & 15);
    const int kg = lane >> 4;  // 0..3

    // prefetch this lane's 32 g values (8 independent dwordx4 in flight)
    float4 gf[8];
    {
        const float* gp = g + (size_t)node * DD + kg * 8;
#pragma unroll
        for (int kc = 0; kc < 4; ++kc) {
            gf[kc * 2]     = *(const float4*)(gp + kc * 32);
            gf[kc * 2 + 1] = *(const float4*)(gp + kc * 32 + 4);
        }
    }

    // split to bf16 hi/lo B-fragments
    bf16x8 gh[4], gl[4];
#pragma unroll
    for (int kc = 0; kc < 4; ++kc) {
        float t[8] = {gf[kc * 2].x,     gf[kc * 2].y,     gf[kc * 2].z,     gf[kc * 2].w,
                      gf[kc * 2 + 1].x, gf[kc * 2 + 1].y, gf[kc * 2 + 1].z, gf[kc * 2 + 1].w};
#pragma unroll
        for (int i = 0; i < 8; ++i) {
            __bf16 hi = (__bf16)t[i];
            float lo = t[i] - (float)hi;
            gh[kc][i] = hi;
            gl[kc][i] = (__bf16)lo;
        }
    }

    f32x4 c[8];
#pragma unroll
    for (int ft = 0; ft < 8; ++ft) c[ft] = (f32x4){0.f, 0.f, 0.f, 0.f};

#pragma unroll
    for (int kc = 0; kc < 4; ++kc) {
#pragma unroll
        for (int ft = 0; ft < 8; ++ft) {
            size_t boff = (size_t)(((ft * 4 + kc) * 64 + lane) * 8);
            bf16x8 wh = *(const bf16x8*)(whi + boff);
            bf16x8 wl = *(const bf16x8*)(wlo + boff);
            c[ft] = __builtin_amdgcn_mfma_f32_16x16x32_bf16(wh, gh[kc], c[ft], 0, 0, 0);
            c[ft] = __builtin_amdgcn_mfma_f32_16x16x32_bf16(wl, gh[kc], c[ft], 0, 0, 0);
            c[ft] = __builtin_amdgcn_mfma_f32_16x16x32_bf16(wh, gl[kc], c[ft], 0, 0, 0);
        }
    }

    // epilogue: lane holds features f = ft*16 + kg*4 + j (j=0..3) of `node`
    if (node < NN) {
        const int f0 = kg * 4;
#pragma unroll
        for (int ft = 0; ft < 8; ++ft) {
            size_t o = (size_t)node * DD + ft * 16 + f0;
            float4 hv = *(const float4*)(h + o);
            float4 bv = *(const float4*)(b + ft * 16 + f0);
            hv.x += fmaxf(c[ft][0] + bv.x, 0.f);
            hv.y += fmaxf(c[ft][1] + bv.y, 0.f);
            hv.z += fmaxf(c[ft][2] + bv.z, 0.f);
            hv.w += fmaxf(c[ft][3] + bv.w, 0.f);
            *(float4*)(h + o) = hv;
        }
    }
}

// ---------------- pool: out[batch[i]] += h[i]  (batch sorted) ----------------

__global__ void pool_kernel(const float* __restrict__ h, const int* __restrict__ batch,
                            float* __restrict__ out) {
    int j = threadIdx.x;  // 128
    int n0 = blockIdx.x * 64;
    float acc = 0.f;
    int prev = -1;
    for (int n = 0; n < 64; ++n) {
        int i = n0 + n;
        if (i >= NN) break;
        int bi = batch[i];
        if (bi != prev) {
            if (prev >= 0) atomicAdd(&out[(size_t)prev * DD + j], acc);
            acc = 0.f;
            prev = bi;
        }
        acc += h[(size_t)i * DD + j];
    }
    if (prev >= 0) atomicAdd(&out[(size_t)prev * DD + j], acc);
}

// ---------------- launch ----------------

static inline size_t align_up(size_t x, size_t a) { return (x + a - 1) & ~(a - 1); }

extern "C" void kernel_launch(void* const* d_in, const int* in_sizes, int n_in,
                              void* d_out, int out_size, void* d_ws, size_t ws_size,
                              hipStream_t stream) {
    const float* x   = (const float*)d_in[0];
    const int*   ei  = (const int*)d_in[1];
    const int*   bat = (const int*)d_in[2];
    const float* We  = (const float*)d_in[4];
    const float* be  = (const float*)d_in[5];
    const float* Wg  = (const float*)d_in[6];
    const float* bg  = (const float*)d_in[7];
    float* out = (float*)d_out;

    // workspace carve-up
    char* p = (char*)d_ws;
    size_t o = 0;
    float* h = (float*)(p + o);       o = align_up(o + (size_t)NN * DD * 4, 512);
    float* g = (float*)(p + o);       o = align_up(o + (size_t)GROWS * DD * 4, 512);
    float* dinv = (float*)(p + o);    o = align_up(o + (size_t)NN * 4, 512);
    int* deg = (int*)(p + o);         o = align_up(o + (size_t)NN * 4, 512);
    int* cursor = (int*)(p + o);      o = align_up(o + (size_t)NN * 4, 512);
    int* off = (int*)(p + o);         o = align_up(o + (size_t)(NN + 1) * 4, 512);
    int* bsums = (int*)(p + o);       o = align_up(o + 512, 512);
    int2* csr = (int2*)(p + o);       o = align_up(o + (size_t)NE * 8, 512);
    unsigned short* whi = (unsigned short*)(p + o); o = align_up(o + (size_t)NL * 16384 * 2, 512);
    unsigned short* wlo = (unsigned short*)(p + o); o = align_up(o + (size_t)NL * 16384 * 2, 512);
    (void)ws_size; (void)in_sizes; (void)n_in; (void)out_size;

    const int GRID_E = (NE + 255) / 256;          // 1563
    const int GRID_SCAN1 = (NN + 1023) / 1024;    // 98
    const int GRID_N256 = (NN + 255) / 256;       // 391
    const int GRID_ND = (size_t)NN * DD / 256;    // 50000
    const int GRID_AGG = NN / 8;                  // 12500
    const int GRID_GEMM = GROWS / 64;             // 1564
    const int GRID_POOL = (NN + 63) / 64;         // 1563
    const int GRID_WPACK = NL * 16384 / 256;      // 320

    // zero deg + cursor (ws is poisoned 0xAA each call)
    hipMemsetAsync(deg, 0, (size_t)NN * 4, stream);
    hipMemsetAsync(cursor, 0, (size_t)NN * 4, stream);
    hipMemsetAsync(out, 0, (size_t)NG * DD * 4, stream);

    deg_kernel<<<GRID_E, 256, 0, stream>>>(ei, deg);
    scan1_kernel<<<GRID_SCAN1, 256, 0, stream>>>(deg, off, bsums);
    scan2_kernel<<<1, 128, 0, stream>>>(bsums, GRID_SCAN1);
    finish_kernel<<<GRID_N256, 256, 0, stream>>>(off, bsums, deg, dinv);
    fill_kernel<<<GRID_E, 256, 0, stream>>>(ei, off, cursor, csr, dinv);
    wpack_kernel<<<GRID_WPACK, 256, 0, stream>>>(Wg, whi, wlo);

    expand_kernel<<<GRID_ND, 256, 0, stream>>>(x, We, be, h);

    for (int l = 0; l < NL; ++l) {
        agg_kernel<<<GRID_AGG, 256, 0, stream>>>(h, g, off, csr, dinv);
        mfma_gemm<<<GRID_GEMM, 256, 0, stream>>>(g, h,
                                                 whi + (size_t)l * 16384,
                                                 wlo + (size_t)l * 16384,
                                                 bg + (size_t)l * DD);
    }

    pool_kernel<<<GRID_POOL, 128, 0, stream>>>(h, bat, out);
}

// Round 9
// 584.141 us; speedup vs baseline: 1.1977x; 1.0240x over previous
//
#include <hip/hip_runtime.h>
#include <hip/hip_bf16.h>

#define NN 100000     // nodes
#define NE 400000     // edges
#define DD 128        // feature dim
#define NG 4096       // graphs
#define NL 5          // layers
#define NF 11         // in features
#define GROWS 100096  // g rows rounded up to 64 (1564 blocks * 64)

typedef __attribute__((ext_vector_type(8))) __bf16 bf16x8;
typedef __attribute__((ext_vector_type(4))) float f32x4;

// ---------------- preprocessing ----------------

__global__ void deg_kernel(const int* __restrict__ ei, int* __restrict__ deg) {
    int e = blockIdx.x * 256 + threadIdx.x;
    if (e < NE) atomicAdd(&deg[ei[NE + e]], 1);
}

// block scans 1024 elements (4 per thread), writes per-block total
__global__ void scan1_kernel(const int* __restrict__ deg, int* __restrict__ off,
                             int* __restrict__ bsums) {
    __shared__ int lds[256];
    int tid = threadIdx.x, b = blockIdx.x;
    int base = b * 1024 + tid * 4;
    int v[4];
#pragma unroll
    for (int q = 0; q < 4; ++q) {
        int i = base + q;
        v[q] = (i < NN) ? deg[i] : 0;
    }
    int s = v[0] + v[1] + v[2] + v[3];
    lds[tid] = s;
    __syncthreads();
    for (int o = 1; o < 256; o <<= 1) {
        int t2 = (tid >= o) ? lds[tid - o] : 0;
        __syncthreads();
        lds[tid] += t2;
        __syncthreads();
    }
    int p = lds[tid] - s;  // exclusive prefix for this thread
#pragma unroll
    for (int q = 0; q < 4; ++q) {
        int i = base + q;
        if (i < NN) off[i] = p;
        p += v[q];
    }
    if (tid == 255) bsums[b] = lds[255];
}

__global__ void scan2_kernel(int* __restrict__ bsums, int nb) {
    __shared__ int lds[128];
    int tid = threadIdx.x;
    int v = (tid < nb) ? bsums[tid] : 0;
    lds[tid] = v;
    __syncthreads();
    for (int o = 1; o < 128; o <<= 1) {
        int t2 = (tid >= o) ? lds[tid - o] : 0;
        __syncthreads();
        lds[tid] += t2;
        __syncthreads();
    }
    if (tid < nb) bsums[tid] = lds[tid] - v;  // exclusive
}

__global__ void finish_kernel(int* __restrict__ off, const int* __restrict__ bsums,
                              const int* __restrict__ deg, float* __restrict__ dinv) {
    int i = blockIdx.x * 256 + threadIdx.x;
    if (i == 0) off[NN] = NE;
    if (i < NN) {
        off[i] += bsums[i >> 10];
        dinv[i] = rsqrtf((float)deg[i] + 2.0f);
    }
}

// packed CSR record: .x = src index, .y = bitcast(norm)
__global__ void fill_kernel(const int* __restrict__ ei, const int* __restrict__ off,
                            int* __restrict__ cursor, int2* __restrict__ csr,
                            const float* __restrict__ dinv) {
    int e = blockIdx.x * 256 + threadIdx.x;
    if (e >= NE) return;
    int s = ei[e];
    int d = ei[NE + e];
    int pos = off[d] + atomicAdd(&cursor[d], 1);
    csr[pos] = make_int2(s, __float_as_int(dinv[s] * dinv[d]));
}

// ---------------- W pre-pack: A-fragment-order bf16 hi/lo (W^T as MFMA A operand) ------
// Layout per layer: [ft(8)][kc(4)][lane(64)][i(8)]; slot (lane,i) holds
// A[row = ft*16 + (lane&15)][k = kc*32 + (lane>>4)*8 + i] = W[k][f].

__global__ void wpack_kernel(const float* __restrict__ Wg, unsigned short* __restrict__ whi,
                             unsigned short* __restrict__ wlo) {
    int t = blockIdx.x * 256 + threadIdx.x;  // < NL*16384
    int l = t >> 14, r = t & 16383;
    int k = r >> 7, n = r & 127;
    float w = Wg[(size_t)l * 16384 + k * 128 + n];
    __bf16 hb = (__bf16)w;
    float lo = w - (float)hb;
    __bf16 lb = (__bf16)lo;
    int ft = n >> 4, kc = k >> 5, lane = (((k >> 3) & 3) << 4) | (n & 15), i = k & 7;
    size_t idx = (size_t)l * 16384 + (((ft * 4 + kc) * 64 + lane) * 8 + i);
    whi[idx] = __builtin_bit_cast(unsigned short, hb);
    wlo[idx] = __builtin_bit_cast(unsigned short, lb);
}

// ---------------- expansion: h = lx @ We + be  (lx = log(x+1) precomputed) ----------------

__global__ void logx_kernel(const float* __restrict__ x, float* __restrict__ lx) {
    int t = blockIdx.x * 256 + threadIdx.x;
    if (t < NN * NF) lx[t] = __logf(x[t] + 1.0f);
}

// block = 2 nodes x 128 cols; 22 staged logs in LDS; 11 FMA per output element.
__global__ __launch_bounds__(256) void expand_kernel(const float* __restrict__ lx,
                                                     const float* __restrict__ We,
                                                     const float* __restrict__ be,
                                                     float* __restrict__ h) {
    __shared__ float ls[2 * NF];
    const int tid = threadIdx.x;
    const int node0 = blockIdx.x * 2;
    if (tid < 2 * NF) ls[tid] = lx[(size_t)node0 * NF + tid];
    __syncthreads();
    const int row = tid >> 7, j = tid & 127;
    float acc = be[j];
#pragma unroll
    for (int f = 0; f < NF; ++f) {
        acc = fmaf(ls[row * NF + f], We[f * DD + j], acc);
    }
    h[(size_t)(node0 + row) * DD + j] = acc;
}

// ---------------- aggregation: g = self_norm*h + sum_e enorm*h[src] ----------------
// 32 lanes per node (float4 per lane), 8 nodes per 256-block.
// PREDICATED 8-unroll: always 8 independent 16B gathers in flight
// (clamped idx -> dup loads are L1 hits; zeroed tail weights).

__global__ __launch_bounds__(256) void agg_kernel(const float* __restrict__ h,
                                                  float* __restrict__ g,
                                                  const int* __restrict__ off,
                                                  const int2* __restrict__ csr,
                                                  const float* __restrict__ dinv) {
    const int tid = threadIdx.x;
    const int node = blockIdx.x * 8 + (tid >> 5);
    const int jj = tid & 31;
    const float4* __restrict__ h4 = (const float4*)h;

    float di = dinv[node];
    float sn = 2.0f * di * di;
    float4 hv = h4[(size_t)node * 32 + jj];
    float4 acc = make_float4(sn * hv.x, sn * hv.y, sn * hv.z, sn * hv.w);

    const int e0 = off[node];
    const int e1 = off[node + 1];
#pragma unroll 1
    for (int e = e0; e < e1; e += 8) {
        const int eL = e1 - 1;
        int2 r[8];
#pragma unroll
        for (int q = 0; q < 8; ++q) r[q] = csr[min(e + q, eL)];
        float4 v[8];
#pragma unroll
        for (int q = 0; q < 8; ++q) v[q] = h4[(size_t)r[q].x * 32 + jj];
#pragma unroll
        for (int q = 0; q < 8; ++q) {
            float w = (e + q < e1) ? __int_as_float(r[q].y) : 0.f;
            acc.x = fmaf(w, v[q].x, acc.x);
            acc.y = fmaf(w, v[q].y, acc.y);
            acc.z = fmaf(w, v[q].z, acc.z);
            acc.w = fmaf(w, v[q].w, acc.w);
        }
    }
    ((float4*)g)[(size_t)node * 32 + jj] = acc;
}

// ---------------- MFMA GEMM (operand-swapped): D = W^T · g^T ----------------
// h[n][:] += relu((g@W)[n][:] + b) computed as D[f][n]; C/D fragment gives each
// lane 4 CONSECUTIVE features of one node -> pure float4 epilogue.
// Wave = 16 nodes x 128 features, no LDS, no barriers.
// 3-term split: Whi*ghi + Wlo*ghi + Whi*glo (fp32 accum).

__global__ __launch_bounds__(256) void mfma_gemm(const float* __restrict__ g,
                                                 float* __restrict__ h,
                                                 const unsigned short* __restrict__ whi,
                                                 const unsigned short* __restrict__ wlo,
                                                 const float* __restrict__ b) {
    const int lane = threadIdx.x & 63;
    const int wv = threadIdx.x >> 6;
    const int node = blockIdx.x * 64 + wv * 16 + (lane & 15);
    const int kg = lane >> 4;  // 0..3

    // prefetch this lane's 32 g values (8 independent dwordx4 in flight)
    float4 gf[8];
    {
        const float* gp = g + (size_t)node * DD + kg * 8;
#pragma unroll
        for (int kc = 0; kc < 4; ++kc) {
            gf[kc * 2]     = *(const float4*)(gp + kc * 32);
            gf[kc * 2 + 1] = *(const float4*)(gp + kc * 32 + 4);
        }
    }

    // split to bf16 hi/lo B-fragments
    bf16x8 gh[4], gl[4];
#pragma unroll
    for (int kc = 0; kc < 4; ++kc) {
        float t[8] = {gf[kc * 2].x,     gf[kc * 2].y,     gf[kc * 2].z,     gf[kc * 2].w,
                      gf[kc * 2 + 1].x, gf[kc * 2 + 1].y, gf[kc * 2 + 1].z, gf[kc * 2 + 1].w};
#pragma unroll
        for (int i = 0; i < 8; ++i) {
            __bf16 hi = (__bf16)t[i];
            float lo = t[i] - (float)hi;
            gh[kc][i] = hi;
            gl[kc][i] = (__bf16)lo;
        }
    }

    f32x4 c[8];
#pragma unroll
    for (int ft = 0; ft < 8; ++ft) c[ft] = (f32x4){0.f, 0.f, 0.f, 0.f};

#pragma unroll
    for (int kc = 0; kc < 4; ++kc) {
#pragma unroll
        for (int ft = 0; ft < 8; ++ft) {
            size_t boff = (size_t)(((ft * 4 + kc) * 64 + lane) * 8);
            bf16x8 wh = *(const bf16x8*)(whi + boff);
            bf16x8 wl = *(const bf16x8*)(wlo + boff);
            c[ft] = __builtin_amdgcn_mfma_f32_16x16x32_bf16(wh, gh[kc], c[ft], 0, 0, 0);
            c[ft] = __builtin_amdgcn_mfma_f32_16x16x32_bf16(wl, gh[kc], c[ft], 0, 0, 0);
            c[ft] = __builtin_amdgcn_mfma_f32_16x16x32_bf16(wh, gl[kc], c[ft], 0, 0, 0);
        }
    }

    // epilogue: lane holds features f = ft*16 + kg*4 + j (j=0..3) of `node`
    if (node < NN) {
        const int f0 = kg * 4;
#pragma unroll
        for (int ft = 0; ft < 8; ++ft) {
            size_t o = (size_t)node * DD + ft * 16 + f0;
            float4 hv = *(const float4*)(h + o);
            float4 bv = *(const float4*)(b + ft * 16 + f0);
            hv.x += fmaxf(c[ft][0] + bv.x, 0.f);
            hv.y += fmaxf(c[ft][1] + bv.y, 0.f);
            hv.z += fmaxf(c[ft][2] + bv.z, 0.f);
            hv.w += fmaxf(c[ft][3] + bv.w, 0.f);
            *(float4*)(h + o) = hv;
        }
    }
}

// ---------------- pool: out[batch[i]] += h[i]  (batch sorted) ----------------

__global__ void pool_kernel(const float* __restrict__ h, const int* __restrict__ batch,
                            float* __restrict__ out) {
    int j = threadIdx.x;  // 128
    int n0 = blockIdx.x * 64;
    float acc = 0.f;
    int prev = -1;
    for (int n = 0; n < 64; ++n) {
        int i = n0 + n;
        if (i >= NN) break;
        int bi = batch[i];
        if (bi != prev) {
            if (prev >= 0) atomicAdd(&out[(size_t)prev * DD + j], acc);
            acc = 0.f;
            prev = bi;
        }
        acc += h[(size_t)i * DD + j];
    }
    if (prev >= 0) atomicAdd(&out[(size_t)prev * DD + j], acc);
}

// ---------------- launch ----------------

static inline size_t align_up(size_t x, size_t a) { return (x + a - 1) & ~(a - 1); }

extern "C" void kernel_launch(void* const* d_in, const int* in_sizes, int n_in,
                              void* d_out, int out_size, void* d_ws, size_t ws_size,
                              hipStream_t stream) {
    const float* x   = (const float*)d_in[0];
    const int*   ei  = (const int*)d_in[1];
    const int*   bat = (const int*)d_in[2];
    const float* We  = (const float*)d_in[4];
    const float* be  = (const float*)d_in[5];
    const float* Wg  = (const float*)d_in[6];
    const float* bg  = (const float*)d_in[7];
    float* out = (float*)d_out;

    // workspace carve-up
    char* p = (char*)d_ws;
    size_t o = 0;
    float* h = (float*)(p + o);       o = align_up(o + (size_t)NN * DD * 4, 512);
    float* g = (float*)(p + o);       o = align_up(o + (size_t)GROWS * DD * 4, 512);
    float* dinv = (float*)(p + o);    o = align_up(o + (size_t)NN * 4, 512);
    int* deg = (int*)(p + o);         o = align_up(o + (size_t)NN * 4, 512);
    int* cursor = (int*)(p + o);      o = align_up(o + (size_t)NN * 4, 512);
    int* off = (int*)(p + o);         o = align_up(o + (size_t)(NN + 1) * 4, 512);
    int* bsums = (int*)(p + o);       o = align_up(o + 512, 512);
    int2* csr = (int2*)(p + o);       o = align_up(o + (size_t)NE * 8, 512);
    unsigned short* whi = (unsigned short*)(p + o); o = align_up(o + (size_t)NL * 16384 * 2, 512);
    unsigned short* wlo = (unsigned short*)(p + o); o = align_up(o + (size_t)NL * 16384 * 2, 512);
    float* lx = (float*)(p + o);      o = align_up(o + (size_t)NN * NF * 4, 512);
    (void)ws_size; (void)in_sizes; (void)n_in; (void)out_size;

    const int GRID_E = (NE + 255) / 256;          // 1563
    const int GRID_SCAN1 = (NN + 1023) / 1024;    // 98
    const int GRID_N256 = (NN + 255) / 256;       // 391
    const int GRID_LOGX = (NN * NF + 255) / 256;  // 4297
    const int GRID_EXP = NN / 2;                  // 50000
    const int GRID_AGG = NN / 8;                  // 12500
    const int GRID_GEMM = GROWS / 64;             // 1564
    const int GRID_POOL = (NN + 63) / 64;         // 1563
    const int GRID_WPACK = NL * 16384 / 256;      // 320

    // zero deg + cursor (ws is poisoned 0xAA each call)
    hipMemsetAsync(deg, 0, (size_t)NN * 4, stream);
    hipMemsetAsync(cursor, 0, (size_t)NN * 4, stream);
    hipMemsetAsync(out, 0, (size_t)NG * DD * 4, stream);

    deg_kernel<<<GRID_E, 256, 0, stream>>>(ei, deg);
    scan1_kernel<<<GRID_SCAN1, 256, 0, stream>>>(deg, off, bsums);
    scan2_kernel<<<1, 128, 0, stream>>>(bsums, GRID_SCAN1);
    finish_kernel<<<GRID_N256, 256, 0, stream>>>(off, bsums, deg, dinv);
    fill_kernel<<<GRID_E, 256, 0, stream>>>(ei, off, cursor, csr, dinv);
    wpack_kernel<<<GRID_WPACK, 256, 0, stream>>>(Wg, whi, wlo);

    logx_kernel<<<GRID_LOGX, 256, 0, stream>>>(x, lx);
    expand_kernel<<<GRID_EXP, 256, 0, stream>>>(lx, We, be, h);

    for (int l = 0; l < NL; ++l) {
        agg_kernel<<<GRID_AGG, 256, 0, stream>>>(h, g, off, csr, dinv);
        mfma_gemm<<<GRID_GEMM, 256, 0, stream>>>(g, h,
                                                 whi + (size_t)l * 16384,
                                                 wlo + (size_t)l * 16384,
                                                 bg + (size_t)l * DD);
    }

    pool_kernel<<<GRID_POOL, 128, 0, stream>>>(h, bat, out);
}